// Round 5
// baseline (250.803 us; speedup 1.0000x reference)
//
#include <hip/hip_runtime.h>

// Problem constants (MultiHeadAttention_9397388443950)
#define B_   2
#define S_   1024
#define SP_  1024
#define L_   2048      // SP + S
#define E_   2048
#define H_   16
#define HD_  128
#define N3_  6144      // 3*E
#define M_   2048      // B*S
#define SCALE_ 0.08838834764831845f   // 1/sqrt(128)

typedef _Float16 f16x8 __attribute__((ext_vector_type(8)));
typedef _Float16 f16x4 __attribute__((ext_vector_type(4)));
typedef _Float16 f16x2 __attribute__((ext_vector_type(2)));
typedef float    f32x4 __attribute__((ext_vector_type(4)));

#define MFMA16(a,b,c) __builtin_amdgcn_mfma_f32_16x16x32_f16(a,b,c,0,0,0)

__device__ __forceinline__ void gload16(const void* g, void* l) {
  __builtin_amdgcn_global_load_lds(
      (const __attribute__((address_space(1))) void*)g,
      (__attribute__((address_space(3))) void*)l, 16, 0, 0);
}

#define SBAR0 __builtin_amdgcn_sched_barrier(0)
#define BARRIER do { SBAR0; __builtin_amdgcn_s_barrier(); SBAR0; } while (0)

// Conflict-free LDS granule layout for [R rows][32 f16] tiles:
// granule(row,cg) = (row>>3)*32 + cg*8 + (row&7)
__device__ __forceinline__ int gstore(int row, int cg) {
  return ((row >> 3) << 5) + (cg << 3) + (row & 7);
}

// ------- merged f32->fp16 convert (x, Wqkv, Wout) + RoPE cos/sin table -------
__global__ __launch_bounds__(256) void k_cvtall(const float* __restrict__ x,
                                                const float* __restrict__ wq,
                                                const float* __restrict__ wo,
                                                _Float16* __restrict__ xh,
                                                _Float16* __restrict__ wh,
                                                _Float16* __restrict__ woh,
                                                float2* __restrict__ cs) {
  int t = blockIdx.x * 256 + threadIdx.x;       // 2,621,440 cvt granules + cs tail
  if (t >= 2621440) {                           // cos/sin table: 131072 entries
    int u = t - 2621440;
    int pos = u >> 7, d = u & 127;
    float inv = exp2f(-(float)(d & 63) * (13.287712379549449f / 64.0f));
    float ang = (float)(SP_ + pos) * inv;
    float s, c;
    sincosf(ang, &s, &c);
    cs[u] = make_float2(c, s);
    return;
  }
  const float* src; _Float16* dst; int off;
  if (t < 524288)       { src = x;  dst = xh;  off = t; }
  else if (t < 2097152) { src = wq; dst = wh;  off = t - 524288; }
  else                  { src = wo; dst = woh; off = t - 2097152; }
  const float4* p = (const float4*)src + (size_t)off * 2;
  float4 a = p[0], b = p[1];
  f16x8 o;
  o[0]=(_Float16)a.x; o[1]=(_Float16)a.y; o[2]=(_Float16)a.z; o[3]=(_Float16)a.w;
  o[4]=(_Float16)b.x; o[5]=(_Float16)b.y; o[6]=(_Float16)b.z; o[7]=(_Float16)b.w;
  *((f16x8*)dst + off) = o;
}

// ---------------- past_key -> Kc rows [0,SP) ----------------
__global__ __launch_bounds__(256) void k_pastk(const float* __restrict__ pk,
                                               _Float16* __restrict__ Kc) {
  int t = blockIdx.x * 256 + threadIdx.x;
  int d8 = t & 15; int rest = t >> 4;
  int pos = rest & 1023; rest >>= 10;
  int h = rest & 15; int b = rest >> 4;
  const float* src = pk + ((size_t)(b * SP_ + pos) * H_ + h) * HD_ + d8 * 8;
  float4 a = *(const float4*)src, c4 = *(const float4*)(src + 4);
  f16x8 o;
  o[0]=(_Float16)a.x;  o[1]=(_Float16)a.y;  o[2]=(_Float16)a.z;  o[3]=(_Float16)a.w;
  o[4]=(_Float16)c4.x; o[5]=(_Float16)c4.y; o[6]=(_Float16)c4.z; o[7]=(_Float16)c4.w;
  *(f16x8*)(Kc + ((size_t)(b * H_ + h) * L_ + pos) * HD_ + d8 * 8) = o;
}

// ---------------- past_value -> Vt (transpose) ----------------
__global__ __launch_bounds__(256) void k_pastv(const float* __restrict__ pv,
                                               _Float16* __restrict__ Vt) {
  __shared__ _Float16 tile[64][72];
  int bh = blockIdx.x; int b = bh >> 4, h = bh & 15;
  int p0 = blockIdx.y * 64, dd0 = blockIdx.z * 64;
  for (int e = threadIdx.x; e < 4096; e += 256) {
    int p = e >> 6, d = e & 63;
    tile[p][d] = (_Float16)pv[((size_t)(b * SP_ + p0 + p) * H_ + h) * HD_ + dd0 + d];
  }
  __syncthreads();
  for (int e = threadIdx.x; e < 4096; e += 256) {
    int d = e >> 6, p = e & 63;
    Vt[((size_t)bh * HD_ + dd0 + d) * L_ + p0 + p] = tile[p][d];
  }
}

// ============ GEMM-8phase: 256x256 tile, BK=64, 8 waves + fused epilogue ====
// K-loop validated in R3. Epilogue: acc -> LDS [256][264], then RoPE (Q/K)
// or transpose (V) written straight to Qh / Kc[SP:] / Vt[:,SP:].
__global__ __launch_bounds__(512, 2) void k_gemm8(const _Float16* __restrict__ A,
                                                  const _Float16* __restrict__ Bw,
                                                  const float2* __restrict__ cs,
                                                  _Float16* __restrict__ Qh,
                                                  _Float16* __restrict__ Kc,
                                                  _Float16* __restrict__ Vt,
                                                  int K, int nbn) {
  __shared__ _Float16 SH[256 * 264];            // 132 KB; pipeline uses first 128 KB
  const int tid = threadIdx.x, w = tid >> 6, lane = tid & 63;
  const int r = lane & 15, g = lane >> 4;
  const int wr = w >> 2, wc = w & 3;
  const int xg = g ^ ((r >> 1) & 3);
  const int nwg = gridDim.x, flat = blockIdx.x, cpx = nwg >> 3;
  const int swz = (flat & 7) * cpx + (flat >> 3);
  const int m0 = (swz / nbn) * 256, n0 = (swz % nbn) * 256;
  const int NT = K >> 6;

  _Float16* const LAp = SH;                     // 4 x 8192
  _Float16* const LBp = SH + 32768;             // 4 x 8192

  auto stage = [&](int hidx) {
    if (hidx >= 4 * NT) return;
    int Ts = hidx >> 2, kind = hidx & 3;
    int kk = kind >> 1, isB = kind & 1;
    const _Float16* src = isB ? Bw : A;
    int rb = isB ? n0 : m0;
    _Float16* slot = (isB ? LBp : LAp) + ((Ts & 1) * 2 + kk) * 8192;
    int kt = (Ts << 6) + (kk << 5);
#pragma unroll
    for (int j = 0; j < 2; j++) {
      int chunk = j * 8 + w;
      int gi = chunk * 64 + lane;
      int row = gi >> 2;
      int cg = (gi & 3) ^ ((gi >> 3) & 3);
      gload16(src + (size_t)(rb + row) * K + kt + cg * 8,
              slot + (size_t)chunk * 512);
    }
  };

  f32x4 acc[8][4] = {};
  f16x8 af[8], bf0, bf1;

#pragma unroll
  for (int h = 0; h < 7; h++) stage(h);
  asm volatile("s_waitcnt vmcnt(6)" ::: "memory");
  BARRIER;

  for (int T = 0; T < NT; ++T) {
    const int d = (T & 1) * 2;
    const _Float16* la0 = LAp + d * 8192;
    const _Float16* lb0 = LBp + d * 8192;
    const _Float16* la1 = LAp + (d + 1) * 8192;
    const _Float16* lb1 = LBp + (d + 1) * 8192;
    // ---- phase 1 ----
#pragma unroll
    for (int mf = 0; mf < 8; mf++)
      af[mf] = *(const f16x8*)(la0 + (wr * 128 + mf * 16 + r) * 32 + xg * 8);
    bf0 = *(const f16x8*)(lb0 + (wc * 64 + r) * 32 + xg * 8);
    bf1 = *(const f16x8*)(lb0 + (wc * 64 + 16 + r) * 32 + xg * 8);
    stage(4 * T + 7);
    BARRIER;
    __builtin_amdgcn_s_setprio(1);
#pragma unroll
    for (int mf = 0; mf < 8; mf++) acc[mf][0] = MFMA16(af[mf], bf0, acc[mf][0]);
#pragma unroll
    for (int mf = 0; mf < 8; mf++) acc[mf][1] = MFMA16(af[mf], bf1, acc[mf][1]);
    __builtin_amdgcn_s_setprio(0);
    BARRIER;
    // ---- phase 2 ----
    bf0 = *(const f16x8*)(lb0 + (wc * 64 + 32 + r) * 32 + xg * 8);
    bf1 = *(const f16x8*)(lb0 + (wc * 64 + 48 + r) * 32 + xg * 8);
    stage(4 * T + 8);
    BARRIER;
    __builtin_amdgcn_s_setprio(1);
#pragma unroll
    for (int mf = 0; mf < 8; mf++) acc[mf][2] = MFMA16(af[mf], bf0, acc[mf][2]);
#pragma unroll
    for (int mf = 0; mf < 8; mf++) acc[mf][3] = MFMA16(af[mf], bf1, acc[mf][3]);
    __builtin_amdgcn_s_setprio(0);
    BARRIER;
    // ---- phase 3 ----
#pragma unroll
    for (int mf = 0; mf < 8; mf++)
      af[mf] = *(const f16x8*)(la1 + (wr * 128 + mf * 16 + r) * 32 + xg * 8);
    bf0 = *(const f16x8*)(lb1 + (wc * 64 + r) * 32 + xg * 8);
    bf1 = *(const f16x8*)(lb1 + (wc * 64 + 16 + r) * 32 + xg * 8);
    stage(4 * T + 9);
    BARRIER;
    __builtin_amdgcn_s_setprio(1);
#pragma unroll
    for (int mf = 0; mf < 8; mf++) acc[mf][0] = MFMA16(af[mf], bf0, acc[mf][0]);
#pragma unroll
    for (int mf = 0; mf < 8; mf++) acc[mf][1] = MFMA16(af[mf], bf1, acc[mf][1]);
    __builtin_amdgcn_s_setprio(0);
    BARRIER;
    // ---- phase 4 ----
    bf0 = *(const f16x8*)(lb1 + (wc * 64 + 32 + r) * 32 + xg * 8);
    bf1 = *(const f16x8*)(lb1 + (wc * 64 + 48 + r) * 32 + xg * 8);
    stage(4 * T + 10);
    BARRIER;
    __builtin_amdgcn_s_setprio(1);
#pragma unroll
    for (int mf = 0; mf < 8; mf++) acc[mf][2] = MFMA16(af[mf], bf0, acc[mf][2]);
#pragma unroll
    for (int mf = 0; mf < 8; mf++) acc[mf][3] = MFMA16(af[mf], bf1, acc[mf][3]);
    __builtin_amdgcn_s_setprio(0);
    if (T < NT - 2) asm volatile("s_waitcnt vmcnt(6)" ::: "memory");
    else            asm volatile("s_waitcnt vmcnt(0)" ::: "memory");
    BARRIER;
  }

  // ===== fused epilogue =====
#pragma unroll
  for (int mf = 0; mf < 8; mf++)
#pragma unroll
    for (int nf = 0; nf < 4; nf++)
#pragma unroll
      for (int q = 0; q < 4; q++) {
        float v = acc[mf][nf][q];
        float vp = __shfl_xor(v, 1);
        if (!(r & 1)) {
          int row = wr * 128 + mf * 16 + g * 4 + q;
          int col = wc * 64 + nf * 16 + r;
          f16x2 pk2; pk2[0] = (_Float16)v; pk2[1] = (_Float16)vp;
          *(f16x2*)&SH[row * 264 + col] = pk2;
        }
      }
  __syncthreads();

  const int seg = n0 >> 11;                    // 0=Q, 1=K, 2=V
  const int h0 = (n0 >> 7) & 15;
  const int bq = m0 >> 10, ib = m0 & 1023;
  if (seg < 2) {
#pragma unroll
    for (int cc = 0; cc < 16; cc++) {
      int cid = cc * 512 + tid;
      int row = cid >> 5, colc = (cid & 31) * 8;
      f16x8 v = *(const f16x8*)&SH[row * 264 + colc];
      int i = ib + row;
      int h = h0 + (colc >> 7), dd = colc & 127;
      const float2* cp = cs + (size_t)i * 128 + dd;
      f16x8 o;
#pragma unroll
      for (int j = 0; j < 4; j++) {
        float e  = (float)v[2 * j], od = (float)v[2 * j + 1];
        float2 c0 = cp[2 * j], c1 = cp[2 * j + 1];
        float e2 = e * c0.x - od * c0.y;
        float o2 = od * c1.x + e * c1.y;
        if (seg == 0) { e2 *= SCALE_; o2 *= SCALE_; }
        o[2 * j] = (_Float16)e2; o[2 * j + 1] = (_Float16)o2;
      }
      if (seg == 0)
        *(f16x8*)(Qh + ((size_t)(bq * H_ + h) * S_ + i) * HD_ + dd) = o;
      else
        *(f16x8*)(Kc + ((size_t)(bq * H_ + h) * L_ + SP_ + i) * HD_ + dd) = o;
    }
  } else {
#pragma unroll
    for (int cc = 0; cc < 16; cc++) {
      int cid = cc * 512 + tid;
      int dcol = cid & 255, i8 = cid >> 8;
      int i0 = i8 * 8;
      f16x8 v;
#pragma unroll
      for (int k = 0; k < 8; k++) v[k] = SH[(i0 + k) * 264 + dcol];
      int h = h0 + (dcol >> 7), dd = dcol & 127;
      *(f16x8*)(Vt + ((size_t)(bq * H_ + h) * HD_ + dd) * L_ + SP_ + ib + i0) = v;
    }
  }
}

// ---------------- GEMM (m97 structure, conflict-free LDS) — out-proj --------
template<bool F16OUT>
__global__ __launch_bounds__(256) void k_gemm(const _Float16* __restrict__ A,
                                              const _Float16* __restrict__ Bw,
                                              void* __restrict__ Cout,
                                              int M, int N, int K) {
  __shared__ _Float16 As[128 * 32];
  __shared__ _Float16 Bs[128 * 32];
  const int tid = threadIdx.x, w = tid >> 6, lane = tid & 63;
  const int r = lane & 15, g = lane >> 4;
  const int m0 = blockIdx.y * 128, n0 = blockIdx.x * 128;
  const int wm = (w >> 1) * 64, wn = (w & 1) * 64;
  f32x4 acc[4][4] = {};
  for (int kt = 0; kt < K; kt += 32) {
#pragma unroll
    for (int it = 0; it < 2; it++) {
      int bg = it * 256 + w * 64;
      int gi = bg + lane;
      int row = ((gi >> 5) << 3) + (gi & 7);
      int cg = (gi >> 3) & 3;
      gload16(A  + (size_t)(m0 + row) * K + kt + cg * 8, &As[bg * 8]);
      gload16(Bw + (size_t)(n0 + row) * K + kt + cg * 8, &Bs[bg * 8]);
    }
    __syncthreads();
    f16x8 af[4], bf[4];
#pragma unroll
    for (int i = 0; i < 4; i++) {
      af[i] = *(const f16x8*)&As[gstore(wm + i * 16 + r, g) * 8];
      bf[i] = *(const f16x8*)&Bs[gstore(wn + i * 16 + r, g) * 8];
    }
#pragma unroll
    for (int i = 0; i < 4; i++)
#pragma unroll
      for (int j = 0; j < 4; j++)
        acc[i][j] = MFMA16(af[i], bf[j], acc[i][j]);
    __syncthreads();
  }
#pragma unroll
  for (int i = 0; i < 4; i++)
#pragma unroll
    for (int j = 0; j < 4; j++)
#pragma unroll
      for (int q = 0; q < 4; q++) {
        size_t idx = (size_t)(m0 + wm + i * 16 + g * 4 + q) * N + n0 + wn + j * 16 + r;
        if constexpr (F16OUT) ((_Float16*)Cout)[idx] = (_Float16)acc[i][j][q];
        else                  ((float*)Cout)[idx]    = acc[i][j][q];
      }
}

// ---------------- Flash attention: 8 waves, 128 q/block, dbuf K/V ----------
// grid (B*H=32, S/128=8). Counted vmcnt(4) keeps next chunk's loads in
// flight across compute (T4); raw s_barrier (no vmcnt(0) drain).
// Ledger: buf^1 last read at chunk c-1; end-of-(c-1) barrier precedes
// stage(c+1) -> no WAR race. vmcnt(4)+barrier retires chunk-c writes
// (each wave issues exactly 4 gloads/chunk) before any wave reads.
__global__ __launch_bounds__(512) void k_attn(const _Float16* __restrict__ Qh,
                                              const _Float16* __restrict__ Kc,
                                              const _Float16* __restrict__ Vt,
                                              _Float16* __restrict__ Oh) {
  __shared__ _Float16 Kl[2][64 * 128];
  __shared__ _Float16 Vl[2][128 * 64];
  __shared__ _Float16 Pl[8][16 * 64];
  const int tid = threadIdx.x, w = tid >> 6, lane = tid & 63;
  const int r = lane & 15, g = lane >> 4;
  const int bh = blockIdx.x, tile = blockIdx.y;
  const int i0 = tile * 128, q0 = i0 + w * 16;
  const _Float16* Kbase = Kc + (size_t)bh * L_ * HD_;
  const _Float16* Vbase = Vt + (size_t)bh * HD_ * L_;
  f16x8 qf[4];
  {
    const _Float16* qp = Qh + ((size_t)bh * S_ + q0 + r) * HD_ + g * 8;
#pragma unroll
    for (int kk = 0; kk < 4; kk++) qf[kk] = *(const f16x8*)(qp + kk * 32);
  }
  f32x4 acc[8] = {};
  float mrun = -1e30f, lrun = 0.f;
  const int lim = SP_ + q0 + r;
  const int nch = (SP_ + i0 + 128) >> 6;

  auto stageKV = [&](int c, int buf) {
    const int c0 = c << 6;
#pragma unroll
    for (int it = 0; it < 2; it++) {
      int bg = it * 512 + w * 64;               // wave-uniform granule base
      int gr = bg + lane;
      int krow = gr >> 4, kc = ((gr & 15) ^ (krow & 7)) * 8;
      gload16(Kbase + (size_t)(c0 + krow) * HD_ + kc, &Kl[buf][bg * 8]);
      int vrow = gr >> 3, vc = ((gr & 7) ^ (vrow & 7)) * 8;
      gload16(Vbase + (size_t)vrow * L_ + c0 + vc, &Vl[buf][bg * 8]);
    }
  };

  stageKV(0, 0);
  for (int c = 0; c < nch; c++) {
    const int c0 = c << 6;
    const int buf = c & 1;
    if (c + 1 < nch) {
      stageKV(c + 1, buf ^ 1);
      asm volatile("s_waitcnt vmcnt(4)" ::: "memory");
    } else {
      asm volatile("s_waitcnt vmcnt(0)" ::: "memory");
    }
    BARRIER;
    // ---- S^T = K * Q^T ----
    f32x4 sc[4] = {};
#pragma unroll
    for (int mf = 0; mf < 4; mf++)
#pragma unroll
      for (int kk = 0; kk < 4; kk++) {
        int row = mf * 16 + r;
        int gran = (g + kk * 4) ^ (row & 7);
        f16x8 kf = *(const f16x8*)&Kl[buf][row * 128 + gran * 8];
        sc[mf] = MFMA16(kf, qf[kk], sc[mf]);
      }
    // ---- mask + online softmax (per-lane row q=r) ----
    float p[4][4];
    float rmax = -1e30f;
#pragma unroll
    for (int mf = 0; mf < 4; mf++)
#pragma unroll
      for (int jj = 0; jj < 4; jj++) {
        float v = sc[mf][jj];
        int kp = c0 + mf * 16 + g * 4 + jj;
        if (kp > lim) v = -1e30f;
        p[mf][jj] = v;
        rmax = fmaxf(rmax, v);
      }
    rmax = fmaxf(rmax, __shfl_xor(rmax, 16));
    rmax = fmaxf(rmax, __shfl_xor(rmax, 32));
    float mnew = fmaxf(mrun, rmax);
    float scale = __expf(mrun - mnew);
    float psum = 0.f;
#pragma unroll
    for (int mf = 0; mf < 4; mf++)
#pragma unroll
      for (int jj = 0; jj < 4; jj++) {
        float e = __expf(p[mf][jj] - mnew);
        p[mf][jj] = e;
        psum += e;
      }
    psum += __shfl_xor(psum, 16);
    psum += __shfl_xor(psum, 32);
    lrun = lrun * scale + psum;
    mrun = mnew;
    // ---- P -> per-wave LDS (same-wave rd-after-wr; in-order DS) ----
#pragma unroll
    for (int mf = 0; mf < 4; mf++) {
      f16x4 ph;
#pragma unroll
      for (int jj = 0; jj < 4; jj++) ph[jj] = (_Float16)p[mf][jj];
      int g16 = (mf * 2 + (g >> 1)) ^ (r & 7);
      *(f16x4*)&Pl[w][r * 64 + g16 * 8 + (g & 1) * 4] = ph;
    }
    // ---- rescale acc ----
    float scj[4];
#pragma unroll
    for (int jj = 0; jj < 4; jj++) scj[jj] = __shfl(scale, g * 4 + jj);
#pragma unroll
    for (int nf = 0; nf < 8; nf++)
#pragma unroll
      for (int jj = 0; jj < 4; jj++) acc[nf][jj] *= scj[jj];
    // ---- O += P * V ----
#pragma unroll
    for (int kk = 0; kk < 2; kk++) {
      f16x8 pf = *(const f16x8*)&Pl[w][r * 64 + ((g + kk * 4) ^ (r & 7)) * 8];
#pragma unroll
      for (int nf = 0; nf < 8; nf++) {
        int vrow = nf * 16 + r;
        int gran = (g + kk * 4) ^ (vrow & 7);
        f16x8 vf = *(const f16x8*)&Vl[buf][vrow * 64 + gran * 8];
        acc[nf] = MFMA16(pf, vf, acc[nf]);
      }
    }
    BARRIER;
  }
  float inv[4];
#pragma unroll
  for (int jj = 0; jj < 4; jj++) inv[jj] = 1.f / __shfl(lrun, g * 4 + jj);
  const int b = bh >> 4, h = bh & 15;
#pragma unroll
  for (int nf = 0; nf < 8; nf++)
#pragma unroll
    for (int jj = 0; jj < 4; jj++) {
      size_t idx = (size_t)(b * S_ + i0 + w * 16 + g * 4 + jj) * E_ + h * HD_ + nf * 16 + r;
      Oh[idx] = (_Float16)(acc[nf][jj] * inv[jj]);
    }
}

extern "C" void kernel_launch(void* const* d_in, const int* in_sizes, int n_in,
                              void* d_out, int out_size, void* d_ws, size_t ws_size,
                              hipStream_t stream) {
  (void)in_sizes; (void)n_in; (void)out_size; (void)ws_size;
  const float* x    = (const float*)d_in[0];
  const float* Wqkv = (const float*)d_in[1];
  const float* Wout = (const float*)d_in[2];
  const float* pk   = (const float*)d_in[3];
  const float* pv   = (const float*)d_in[4];

  char* ws = (char*)d_ws;
  _Float16* Xh   = (_Float16*)(ws);               // 8.39MB (reused as Oh)
  _Float16* Wh   = (_Float16*)(ws + 8388608);     // 25.2MB
  _Float16* Qhb  = (_Float16*)(ws + 33554432);    // 8.39MB
  _Float16* Kcb  = (_Float16*)(ws + 41943040);    // 16.8MB
  _Float16* Vtb  = (_Float16*)(ws + 58720256);    // 16.8MB
  float2*   cs   = (float2*)  (ws + 75497472);    // 1MB
  _Float16* Woh  = (_Float16*)(ws + 76546048);    // 8.39MB  (total ~85MB)
  _Float16* Ohb  = Xh;

  k_cvtall<<<10752, 256, 0, stream>>>(x, Wqkv, Wout, Xh, Wh, Woh, cs);
  k_pastk <<<2048,  256, 0, stream>>>(pk, Kcb);
  k_pastv <<<dim3(32, 16, 2), 256, 0, stream>>>(pv, Vtb);
  k_gemm8 <<<192, 512, 0, stream>>>(Xh, Wh, cs, Qhb, Kcb, Vtb, E_, 24);
  k_attn  <<<dim3(32, 8), 512, 0, stream>>>(Qhb, Kcb, Vtb, Ohb);
  k_gemm<false><<<dim3(16, 16), 256, 0, stream>>>(Ohb, Woh, d_out, M_, E_, E_);
}

// Round 6
// 241.648 us; speedup vs baseline: 1.0379x; 1.0379x over previous
//
#include <hip/hip_runtime.h>

// Problem constants (MultiHeadAttention_9397388443950)
#define B_   2
#define S_   1024
#define SP_  1024
#define L_   2048      // SP + S
#define E_   2048
#define H_   16
#define HD_  128
#define N3_  6144      // 3*E
#define M_   2048      // B*S
#define SCALE_ 0.08838834764831845f   // 1/sqrt(128)

typedef _Float16 f16x8 __attribute__((ext_vector_type(8)));
typedef _Float16 f16x4 __attribute__((ext_vector_type(4)));
typedef _Float16 f16x2 __attribute__((ext_vector_type(2)));
typedef float    f32x4 __attribute__((ext_vector_type(4)));

#define MFMA16(a,b,c) __builtin_amdgcn_mfma_f32_16x16x32_f16(a,b,c,0,0,0)

__device__ __forceinline__ void gload16(const void* g, void* l) {
  __builtin_amdgcn_global_load_lds(
      (const __attribute__((address_space(1))) void*)g,
      (__attribute__((address_space(3))) void*)l, 16, 0, 0);
}

#define SBAR0 __builtin_amdgcn_sched_barrier(0)
#define BARRIER do { SBAR0; __builtin_amdgcn_s_barrier(); SBAR0; } while (0)

// ------- merged f32->fp16 convert (x, Wqkv, Wout) + RoPE cos/sin table -------
__global__ __launch_bounds__(256) void k_cvtall(const float* __restrict__ x,
                                                const float* __restrict__ wq,
                                                const float* __restrict__ wo,
                                                _Float16* __restrict__ xh,
                                                _Float16* __restrict__ wh,
                                                _Float16* __restrict__ woh,
                                                float2* __restrict__ cs) {
  int t = blockIdx.x * 256 + threadIdx.x;       // 2,621,440 cvt granules + cs tail
  if (t >= 2621440) {                           // cos/sin table: 131072 entries
    int u = t - 2621440;
    int pos = u >> 7, d = u & 127;
    float inv = exp2f(-(float)(d & 63) * (13.287712379549449f / 64.0f));
    float ang = (float)(SP_ + pos) * inv;
    float s, c;
    sincosf(ang, &s, &c);
    cs[u] = make_float2(c, s);
    return;
  }
  const float* src; _Float16* dst; int off;
  if (t < 524288)       { src = x;  dst = xh;  off = t; }
  else if (t < 2097152) { src = wq; dst = wh;  off = t - 524288; }
  else                  { src = wo; dst = woh; off = t - 2097152; }
  const float4* p = (const float4*)src + (size_t)off * 2;
  float4 a = p[0], b = p[1];
  f16x8 o;
  o[0]=(_Float16)a.x; o[1]=(_Float16)a.y; o[2]=(_Float16)a.z; o[3]=(_Float16)a.w;
  o[4]=(_Float16)b.x; o[5]=(_Float16)b.y; o[6]=(_Float16)b.z; o[7]=(_Float16)b.w;
  *((f16x8*)dst + off) = o;
}

// ---------------- past_key -> Kc rows [0,SP) ----------------
__global__ __launch_bounds__(256) void k_pastk(const float* __restrict__ pk,
                                               _Float16* __restrict__ Kc) {
  int t = blockIdx.x * 256 + threadIdx.x;
  int d8 = t & 15; int rest = t >> 4;
  int pos = rest & 1023; rest >>= 10;
  int h = rest & 15; int b = rest >> 4;
  const float* src = pk + ((size_t)(b * SP_ + pos) * H_ + h) * HD_ + d8 * 8;
  float4 a = *(const float4*)src, c4 = *(const float4*)(src + 4);
  f16x8 o;
  o[0]=(_Float16)a.x;  o[1]=(_Float16)a.y;  o[2]=(_Float16)a.z;  o[3]=(_Float16)a.w;
  o[4]=(_Float16)c4.x; o[5]=(_Float16)c4.y; o[6]=(_Float16)c4.z; o[7]=(_Float16)c4.w;
  *(f16x8*)(Kc + ((size_t)(b * H_ + h) * L_ + pos) * HD_ + d8 * 8) = o;
}

// ---------------- past_value -> Vt (transpose) ----------------
__global__ __launch_bounds__(256) void k_pastv(const float* __restrict__ pv,
                                               _Float16* __restrict__ Vt) {
  __shared__ _Float16 tile[64][72];
  int bh = blockIdx.x; int b = bh >> 4, h = bh & 15;
  int p0 = blockIdx.y * 64, dd0 = blockIdx.z * 64;
  for (int e = threadIdx.x; e < 4096; e += 256) {
    int p = e >> 6, d = e & 63;
    tile[p][d] = (_Float16)pv[((size_t)(b * SP_ + p0 + p) * H_ + h) * HD_ + dd0 + d];
  }
  __syncthreads();
  for (int e = threadIdx.x; e < 4096; e += 256) {
    int d = e >> 6, p = e & 63;
    Vt[((size_t)bh * HD_ + dd0 + d) * L_ + p0 + p] = tile[p][d];
  }
}

// ============ GEMM-8phase: 256x256 tile, BK=64, 8 waves + fused epilogue ====
// K-loop validated in R3. Epilogue: acc -> LDS [256][264], then RoPE (Q/K)
// or transpose (V) written straight to Qh / Kc[SP:] / Vt[:,SP:].
__global__ __launch_bounds__(512, 2) void k_gemm8(const _Float16* __restrict__ A,
                                                  const _Float16* __restrict__ Bw,
                                                  const float2* __restrict__ cs,
                                                  _Float16* __restrict__ Qh,
                                                  _Float16* __restrict__ Kc,
                                                  _Float16* __restrict__ Vt,
                                                  int K, int nbn) {
  __shared__ _Float16 SH[256 * 264];            // 132 KB; pipeline uses first 128 KB
  const int tid = threadIdx.x, w = tid >> 6, lane = tid & 63;
  const int r = lane & 15, g = lane >> 4;
  const int wr = w >> 2, wc = w & 3;
  const int xg = g ^ ((r >> 1) & 3);
  const int nwg = gridDim.x, flat = blockIdx.x, cpx = nwg >> 3;
  const int swz = (flat & 7) * cpx + (flat >> 3);
  const int m0 = (swz / nbn) * 256, n0 = (swz % nbn) * 256;
  const int NT = K >> 6;

  _Float16* const LAp = SH;                     // 4 x 8192
  _Float16* const LBp = SH + 32768;             // 4 x 8192

  auto stage = [&](int hidx) {
    if (hidx >= 4 * NT) return;
    int Ts = hidx >> 2, kind = hidx & 3;
    int kk = kind >> 1, isB = kind & 1;
    const _Float16* src = isB ? Bw : A;
    int rb = isB ? n0 : m0;
    _Float16* slot = (isB ? LBp : LAp) + ((Ts & 1) * 2 + kk) * 8192;
    int kt = (Ts << 6) + (kk << 5);
#pragma unroll
    for (int j = 0; j < 2; j++) {
      int chunk = j * 8 + w;
      int gi = chunk * 64 + lane;
      int row = gi >> 2;
      int cg = (gi & 3) ^ ((gi >> 3) & 3);
      gload16(src + (size_t)(rb + row) * K + kt + cg * 8,
              slot + (size_t)chunk * 512);
    }
  };

  f32x4 acc[8][4] = {};
  f16x8 af[8], bf0, bf1;

#pragma unroll
  for (int h = 0; h < 7; h++) stage(h);
  asm volatile("s_waitcnt vmcnt(6)" ::: "memory");
  BARRIER;

  for (int T = 0; T < NT; ++T) {
    const int d = (T & 1) * 2;
    const _Float16* la0 = LAp + d * 8192;
    const _Float16* lb0 = LBp + d * 8192;
    const _Float16* la1 = LAp + (d + 1) * 8192;
    const _Float16* lb1 = LBp + (d + 1) * 8192;
    // ---- phase 1 ----
#pragma unroll
    for (int mf = 0; mf < 8; mf++)
      af[mf] = *(const f16x8*)(la0 + (wr * 128 + mf * 16 + r) * 32 + xg * 8);
    bf0 = *(const f16x8*)(lb0 + (wc * 64 + r) * 32 + xg * 8);
    bf1 = *(const f16x8*)(lb0 + (wc * 64 + 16 + r) * 32 + xg * 8);
    stage(4 * T + 7);
    BARRIER;
    __builtin_amdgcn_s_setprio(1);
#pragma unroll
    for (int mf = 0; mf < 8; mf++) acc[mf][0] = MFMA16(af[mf], bf0, acc[mf][0]);
#pragma unroll
    for (int mf = 0; mf < 8; mf++) acc[mf][1] = MFMA16(af[mf], bf1, acc[mf][1]);
    __builtin_amdgcn_s_setprio(0);
    BARRIER;
    // ---- phase 2 ----
    bf0 = *(const f16x8*)(lb0 + (wc * 64 + 32 + r) * 32 + xg * 8);
    bf1 = *(const f16x8*)(lb0 + (wc * 64 + 48 + r) * 32 + xg * 8);
    stage(4 * T + 8);
    BARRIER;
    __builtin_amdgcn_s_setprio(1);
#pragma unroll
    for (int mf = 0; mf < 8; mf++) acc[mf][2] = MFMA16(af[mf], bf0, acc[mf][2]);
#pragma unroll
    for (int mf = 0; mf < 8; mf++) acc[mf][3] = MFMA16(af[mf], bf1, acc[mf][3]);
    __builtin_amdgcn_s_setprio(0);
    BARRIER;
    // ---- phase 3 ----
#pragma unroll
    for (int mf = 0; mf < 8; mf++)
      af[mf] = *(const f16x8*)(la1 + (wr * 128 + mf * 16 + r) * 32 + xg * 8);
    bf0 = *(const f16x8*)(lb1 + (wc * 64 + r) * 32 + xg * 8);
    bf1 = *(const f16x8*)(lb1 + (wc * 64 + 16 + r) * 32 + xg * 8);
    stage(4 * T + 9);
    BARRIER;
    __builtin_amdgcn_s_setprio(1);
#pragma unroll
    for (int mf = 0; mf < 8; mf++) acc[mf][0] = MFMA16(af[mf], bf0, acc[mf][0]);
#pragma unroll
    for (int mf = 0; mf < 8; mf++) acc[mf][1] = MFMA16(af[mf], bf1, acc[mf][1]);
    __builtin_amdgcn_s_setprio(0);
    BARRIER;
    // ---- phase 4 ----
    bf0 = *(const f16x8*)(lb1 + (wc * 64 + 32 + r) * 32 + xg * 8);
    bf1 = *(const f16x8*)(lb1 + (wc * 64 + 48 + r) * 32 + xg * 8);
    stage(4 * T + 10);
    BARRIER;
    __builtin_amdgcn_s_setprio(1);
#pragma unroll
    for (int mf = 0; mf < 8; mf++) acc[mf][2] = MFMA16(af[mf], bf0, acc[mf][2]);
#pragma unroll
    for (int mf = 0; mf < 8; mf++) acc[mf][3] = MFMA16(af[mf], bf1, acc[mf][3]);
    __builtin_amdgcn_s_setprio(0);
    if (T < NT - 2) asm volatile("s_waitcnt vmcnt(6)" ::: "memory");
    else            asm volatile("s_waitcnt vmcnt(0)" ::: "memory");
    BARRIER;
  }

  // ===== fused epilogue =====
#pragma unroll
  for (int mf = 0; mf < 8; mf++)
#pragma unroll
    for (int nf = 0; nf < 4; nf++)
#pragma unroll
      for (int q = 0; q < 4; q++) {
        float v = acc[mf][nf][q];
        float vp = __shfl_xor(v, 1);
        if (!(r & 1)) {
          int row = wr * 128 + mf * 16 + g * 4 + q;
          int col = wc * 64 + nf * 16 + r;
          f16x2 pk2; pk2[0] = (_Float16)v; pk2[1] = (_Float16)vp;
          *(f16x2*)&SH[row * 264 + col] = pk2;
        }
      }
  __syncthreads();

  const int seg = n0 >> 11;                    // 0=Q, 1=K, 2=V
  const int h0 = (n0 >> 7) & 15;
  const int bq = m0 >> 10, ib = m0 & 1023;
  if (seg < 2) {
#pragma unroll
    for (int cc = 0; cc < 16; cc++) {
      int cid = cc * 512 + tid;
      int row = cid >> 5, colc = (cid & 31) * 8;
      f16x8 v = *(const f16x8*)&SH[row * 264 + colc];
      int i = ib + row;
      int h = h0 + (colc >> 7), dd = colc & 127;
      const float2* cp = cs + (size_t)i * 128 + dd;
      f16x8 o;
#pragma unroll
      for (int j = 0; j < 4; j++) {
        float e  = (float)v[2 * j], od = (float)v[2 * j + 1];
        float2 c0 = cp[2 * j], c1 = cp[2 * j + 1];
        float e2 = e * c0.x - od * c0.y;
        float o2 = od * c1.x + e * c1.y;
        if (seg == 0) { e2 *= SCALE_; o2 *= SCALE_; }
        o[2 * j] = (_Float16)e2; o[2 * j + 1] = (_Float16)o2;
      }
      if (seg == 0)
        *(f16x8*)(Qh + ((size_t)(bq * H_ + h) * S_ + i) * HD_ + dd) = o;
      else
        *(f16x8*)(Kc + ((size_t)(bq * H_ + h) * L_ + SP_ + i) * HD_ + dd) = o;
    }
  } else {
#pragma unroll
    for (int cc = 0; cc < 16; cc++) {
      int cid = cc * 512 + tid;
      int dcol = cid & 255, i8 = cid >> 8;
      int i0 = i8 * 8;
      f16x8 v;
#pragma unroll
      for (int k = 0; k < 8; k++) v[k] = SH[(i0 + k) * 264 + dcol];
      int h = h0 + (dcol >> 7), dd = dcol & 127;
      *(f16x8*)(Vt + ((size_t)(bq * H_ + h) * HD_ + dd) * L_ + SP_ + ib + i0) = v;
    }
  }
}

// ======= out-proj: 8-phase 256x256 split-K x4, atomic-f32 accumulate ========
// grid 256 = 64 (mn) x 4 (ks); each block K-slice 512 (NT=8). Epilogue
// unsafeAtomicAdd f32 into d_out (zeroed by hipMemsetAsync). Consecutive
// swz share ks (swz>>6) -> each XCD works one contiguous (ks, mn) chunk.
__global__ __launch_bounds__(512, 2) void k_gemm8o(const _Float16* __restrict__ A,
                                                   const _Float16* __restrict__ Bw,
                                                   float* __restrict__ Cf) {
  __shared__ _Float16 LA[4][8192];
  __shared__ _Float16 LB[4][8192];
  const int tid = threadIdx.x, w = tid >> 6, lane = tid & 63;
  const int r = lane & 15, g = lane >> 4;
  const int wr = w >> 2, wc = w & 3;
  const int xg = g ^ ((r >> 1) & 3);
  const int nwg = gridDim.x, flat = blockIdx.x, cpx = nwg >> 3;   // 256, 32
  const int swz = (flat & 7) * cpx + (flat >> 3);
  const int mn = swz & 63, ks = swz >> 6;
  const int m0 = (mn >> 3) * 256, n0 = (mn & 7) * 256;
  const int ko = ks * 512;
  const int K = E_, N = E_;
  const int NT = 8;                             // 512 / 64

  auto stage = [&](int hidx) {
    if (hidx >= 4 * NT) return;
    int Ts = hidx >> 2, kind = hidx & 3;
    int kk = kind >> 1, isB = kind & 1;
    const _Float16* src = isB ? Bw : A;
    int rb = isB ? n0 : m0;
    _Float16* slot = (isB ? &LB[0][0] : &LA[0][0]) + ((Ts & 1) * 2 + kk) * 8192;
    int kt = ko + (Ts << 6) + (kk << 5);
#pragma unroll
    for (int j = 0; j < 2; j++) {
      int chunk = j * 8 + w;
      int gi = chunk * 64 + lane;
      int row = gi >> 2;
      int cg = (gi & 3) ^ ((gi >> 3) & 3);
      gload16(src + (size_t)(rb + row) * K + kt + cg * 8,
              slot + (size_t)chunk * 512);
    }
  };

  f32x4 acc[8][4] = {};
  f16x8 af[8], bf0, bf1;

#pragma unroll
  for (int h = 0; h < 7; h++) stage(h);
  asm volatile("s_waitcnt vmcnt(6)" ::: "memory");
  BARRIER;

  for (int T = 0; T < NT; ++T) {
    const int d = (T & 1) * 2;
    const _Float16* la0 = &LA[d][0];
    const _Float16* lb0 = &LB[d][0];
    const _Float16* la1 = &LA[d + 1][0];
    const _Float16* lb1 = &LB[d + 1][0];
    // ---- phase 1 ----
#pragma unroll
    for (int mf = 0; mf < 8; mf++)
      af[mf] = *(const f16x8*)(la0 + (wr * 128 + mf * 16 + r) * 32 + xg * 8);
    bf0 = *(const f16x8*)(lb0 + (wc * 64 + r) * 32 + xg * 8);
    bf1 = *(const f16x8*)(lb0 + (wc * 64 + 16 + r) * 32 + xg * 8);
    stage(4 * T + 7);
    BARRIER;
    __builtin_amdgcn_s_setprio(1);
#pragma unroll
    for (int mf = 0; mf < 8; mf++) acc[mf][0] = MFMA16(af[mf], bf0, acc[mf][0]);
#pragma unroll
    for (int mf = 0; mf < 8; mf++) acc[mf][1] = MFMA16(af[mf], bf1, acc[mf][1]);
    __builtin_amdgcn_s_setprio(0);
    BARRIER;
    // ---- phase 2 ----
    bf0 = *(const f16x8*)(lb0 + (wc * 64 + 32 + r) * 32 + xg * 8);
    bf1 = *(const f16x8*)(lb0 + (wc * 64 + 48 + r) * 32 + xg * 8);
    stage(4 * T + 8);
    BARRIER;
    __builtin_amdgcn_s_setprio(1);
#pragma unroll
    for (int mf = 0; mf < 8; mf++) acc[mf][2] = MFMA16(af[mf], bf0, acc[mf][2]);
#pragma unroll
    for (int mf = 0; mf < 8; mf++) acc[mf][3] = MFMA16(af[mf], bf1, acc[mf][3]);
    __builtin_amdgcn_s_setprio(0);
    BARRIER;
    // ---- phase 3 ----
#pragma unroll
    for (int mf = 0; mf < 8; mf++)
      af[mf] = *(const f16x8*)(la1 + (wr * 128 + mf * 16 + r) * 32 + xg * 8);
    bf0 = *(const f16x8*)(lb1 + (wc * 64 + r) * 32 + xg * 8);
    bf1 = *(const f16x8*)(lb1 + (wc * 64 + 16 + r) * 32 + xg * 8);
    stage(4 * T + 9);
    BARRIER;
    __builtin_amdgcn_s_setprio(1);
#pragma unroll
    for (int mf = 0; mf < 8; mf++) acc[mf][0] = MFMA16(af[mf], bf0, acc[mf][0]);
#pragma unroll
    for (int mf = 0; mf < 8; mf++) acc[mf][1] = MFMA16(af[mf], bf1, acc[mf][1]);
    __builtin_amdgcn_s_setprio(0);
    BARRIER;
    // ---- phase 4 ----
    bf0 = *(const f16x8*)(lb1 + (wc * 64 + 32 + r) * 32 + xg * 8);
    bf1 = *(const f16x8*)(lb1 + (wc * 64 + 48 + r) * 32 + xg * 8);
    stage(4 * T + 10);
    BARRIER;
    __builtin_amdgcn_s_setprio(1);
#pragma unroll
    for (int mf = 0; mf < 8; mf++) acc[mf][2] = MFMA16(af[mf], bf0, acc[mf][2]);
#pragma unroll
    for (int mf = 0; mf < 8; mf++) acc[mf][3] = MFMA16(af[mf], bf1, acc[mf][3]);
    __builtin_amdgcn_s_setprio(0);
    if (T < NT - 2) asm volatile("s_waitcnt vmcnt(6)" ::: "memory");
    else            asm volatile("s_waitcnt vmcnt(0)" ::: "memory");
    BARRIER;
  }

  // epilogue: atomic f32 accumulate into d_out
#pragma unroll
  for (int mf = 0; mf < 8; mf++)
#pragma unroll
    for (int nf = 0; nf < 4; nf++)
#pragma unroll
      for (int q = 0; q < 4; q++) {
        size_t idx = (size_t)(m0 + wr * 128 + mf * 16 + g * 4 + q) * N
                   + n0 + wc * 64 + nf * 16 + r;
        unsafeAtomicAdd(&Cf[idx], acc[mf][nf][q]);
      }
}

// ---------------- Flash attention (R4-validated 4-wave structure) ----------
__global__ __launch_bounds__(256) void k_attn(const _Float16* __restrict__ Qh,
                                              const _Float16* __restrict__ Kc,
                                              const _Float16* __restrict__ Vt,
                                              _Float16* __restrict__ Oh) {
  __shared__ _Float16 Kl[64 * 128];
  __shared__ _Float16 Vl[128 * 64];
  __shared__ _Float16 Pl[4][16 * 64];
  const int tid = threadIdx.x, w = tid >> 6, lane = tid & 63;
  const int r = lane & 15, g = lane >> 4;
  const int bh = blockIdx.x, tile = blockIdx.y;
  const int i0 = tile * 64, q0 = i0 + w * 16;
  const _Float16* Kbase = Kc + (size_t)bh * L_ * HD_;
  const _Float16* Vbase = Vt + (size_t)bh * HD_ * L_;
  f16x8 qf[4];
  {
    const _Float16* qp = Qh + ((size_t)bh * S_ + q0 + r) * HD_ + g * 8;
#pragma unroll
    for (int kk = 0; kk < 4; kk++) qf[kk] = *(const f16x8*)(qp + kk * 32);
  }
  f32x4 acc[8] = {};
  float mrun = -1e30f, lrun = 0.f;
  const int lim = SP_ + q0 + r;
  const int nch = (SP_ + i0 + 64) >> 6;
  for (int c = 0; c < nch; c++) {
    const int c0 = c << 6;
#pragma unroll
    for (int it = 0; it < 4; it++) {
      int bg = it * 256 + w * 64;
      int gr = bg + lane;
      int krow = gr >> 4, kc = ((gr & 15) ^ (krow & 7)) * 8;
      gload16(Kbase + (size_t)(c0 + krow) * HD_ + kc, &Kl[bg * 8]);
      int vrow = gr >> 3, vc = ((gr & 7) ^ (vrow & 7)) * 8;
      gload16(Vbase + (size_t)vrow * L_ + c0 + vc, &Vl[bg * 8]);
    }
    __syncthreads();
    f32x4 sc[4] = {};
#pragma unroll
    for (int mf = 0; mf < 4; mf++)
#pragma unroll
      for (int kk = 0; kk < 4; kk++) {
        int row = mf * 16 + r;
        int gran = (g + kk * 4) ^ (row & 7);
        f16x8 kf = *(const f16x8*)&Kl[row * 128 + gran * 8];
        sc[mf] = MFMA16(kf, qf[kk], sc[mf]);
      }
    float p[4][4];
    float rmax = -1e30f;
#pragma unroll
    for (int mf = 0; mf < 4; mf++)
#pragma unroll
      for (int jj = 0; jj < 4; jj++) {
        float v = sc[mf][jj];
        int kp = c0 + mf * 16 + g * 4 + jj;
        if (kp > lim) v = -1e30f;
        p[mf][jj] = v;
        rmax = fmaxf(rmax, v);
      }
    rmax = fmaxf(rmax, __shfl_xor(rmax, 16));
    rmax = fmaxf(rmax, __shfl_xor(rmax, 32));
    float mnew = fmaxf(mrun, rmax);
    float scale = __expf(mrun - mnew);
    float psum = 0.f;
#pragma unroll
    for (int mf = 0; mf < 4; mf++)
#pragma unroll
      for (int jj = 0; jj < 4; jj++) {
        float e = __expf(p[mf][jj] - mnew);
        p[mf][jj] = e;
        psum += e;
      }
    psum += __shfl_xor(psum, 16);
    psum += __shfl_xor(psum, 32);
    lrun = lrun * scale + psum;
    mrun = mnew;
#pragma unroll
    for (int mf = 0; mf < 4; mf++) {
      f16x4 ph;
#pragma unroll
      for (int jj = 0; jj < 4; jj++) ph[jj] = (_Float16)p[mf][jj];
      int g16 = (mf * 2 + (g >> 1)) ^ (r & 7);
      *(f16x4*)&Pl[w][r * 64 + g16 * 8 + (g & 1) * 4] = ph;
    }
    float scj[4];
#pragma unroll
    for (int jj = 0; jj < 4; jj++) scj[jj] = __shfl(scale, g * 4 + jj);
#pragma unroll
    for (int nf = 0; nf < 8; nf++)
#pragma unroll
      for (int jj = 0; jj < 4; jj++) acc[nf][jj] *= scj[jj];
#pragma unroll
    for (int kk = 0; kk < 2; kk++) {
      f16x8 pf = *(const f16x8*)&Pl[w][r * 64 + ((g + kk * 4) ^ (r & 7)) * 8];
#pragma unroll
      for (int nf = 0; nf < 8; nf++) {
        int vrow = nf * 16 + r;
        int gran = (g + kk * 4) ^ (vrow & 7);
        f16x8 vf = *(const f16x8*)&Vl[vrow * 64 + gran * 8];
        acc[nf] = MFMA16(pf, vf, acc[nf]);
      }
    }
    __syncthreads();
  }
  float inv[4];
#pragma unroll
  for (int jj = 0; jj < 4; jj++) inv[jj] = 1.f / __shfl(lrun, g * 4 + jj);
  const int b = bh >> 4, h = bh & 15;
#pragma unroll
  for (int nf = 0; nf < 8; nf++)
#pragma unroll
    for (int jj = 0; jj < 4; jj++) {
      size_t idx = (size_t)(b * S_ + i0 + w * 16 + g * 4 + jj) * E_ + h * HD_ + nf * 16 + r;
      Oh[idx] = (_Float16)(acc[nf][jj] * inv[jj]);
    }
}

extern "C" void kernel_launch(void* const* d_in, const int* in_sizes, int n_in,
                              void* d_out, int out_size, void* d_ws, size_t ws_size,
                              hipStream_t stream) {
  (void)in_sizes; (void)n_in; (void)ws_size;
  const float* x    = (const float*)d_in[0];
  const float* Wqkv = (const float*)d_in[1];
  const float* Wout = (const float*)d_in[2];
  const float* pk   = (const float*)d_in[3];
  const float* pv   = (const float*)d_in[4];

  char* ws = (char*)d_ws;
  _Float16* Xh   = (_Float16*)(ws);               // 8.39MB (reused as Oh)
  _Float16* Wh   = (_Float16*)(ws + 8388608);     // 25.2MB
  _Float16* Qhb  = (_Float16*)(ws + 33554432);    // 8.39MB
  _Float16* Kcb  = (_Float16*)(ws + 41943040);    // 16.8MB
  _Float16* Vtb  = (_Float16*)(ws + 58720256);    // 16.8MB
  float2*   cs   = (float2*)  (ws + 75497472);    // 1MB
  _Float16* Woh  = (_Float16*)(ws + 76546048);    // 8.39MB  (total ~85MB)
  _Float16* Ohb  = Xh;

  hipMemsetAsync(d_out, 0, (size_t)out_size * sizeof(float), stream);
  k_cvtall<<<10752, 256, 0, stream>>>(x, Wqkv, Wout, Xh, Wh, Woh, cs);
  k_pastk <<<2048,  256, 0, stream>>>(pk, Kcb);
  k_pastv <<<dim3(32, 16, 2), 256, 0, stream>>>(pv, Vtb);
  k_gemm8 <<<192, 512, 0, stream>>>(Xh, Wh, cs, Qhb, Kcb, Vtb, E_, 24);
  k_attn  <<<dim3(32, 16), 256, 0, stream>>>(Qhb, Kcb, Vtb, Ohb);
  k_gemm8o<<<256, 512, 0, stream>>>(Ohb, Woh, (float*)d_out);
}